// Round 10
// baseline (196.760 us; speedup 1.0000x reference)
//
#include <hip/hip_runtime.h>

#define N_TOK 4096
#define C_DIM 512
#define CI_DIM 128
#define B_DIM 4
#define KVSPLIT 4
#define RESCALE_THR 8.0f

typedef unsigned short u16;
typedef unsigned int u32;
typedef unsigned long long u64;
typedef __attribute__((ext_vector_type(8))) short bf16x8;
typedef __attribute__((ext_vector_type(4))) float f32x4;
typedef __attribute__((ext_vector_type(8))) unsigned short u16x8;
typedef __attribute__((ext_vector_type(4))) float float4v;

// alias-safe views of the P tile (stored as u64, read back as bf16x8)
typedef unsigned long long __attribute__((may_alias)) u64a;
typedef bf16x8 __attribute__((may_alias)) bf16x8a;

__device__ __forceinline__ u16 f2bf(float f) {
    union { float f; u32 u; } v; v.f = f;
    u32 r = (v.u + 0x7fffu + ((v.u >> 16) & 1u)) >> 16;
    return (u16)r;
}
__device__ __forceinline__ float bf2f(u16 h) {
    union { u32 u; float f; } v; v.u = (u32)h << 16;
    return v.f;
}
__device__ __forceinline__ u32 cvt_pk_bf16(float a, float b) {
    u32 r;
    asm("v_cvt_pk_bf16_f32 %0, %1, %2" : "=v"(r) : "v"(a), "v"(b));
    return r;
}

// ---------------------------------------------------------------------------
// Prepass 1: transpose+convert x f32 [B][C][N] -> xT bf16 [B][N][C]
// ---------------------------------------------------------------------------
__global__ __launch_bounds__(256) void xpose_kernel(
    const float* __restrict__ x, u16* __restrict__ xT)
{
    const int n0 = blockIdx.x * 64;
    const int c0 = blockIdx.y * 64;
    const int b  = blockIdx.z;
    __shared__ u16 Ts[64][72];
    const int t = threadIdx.x;

    const float* xb = x + (size_t)b * C_DIM * N_TOK;
    for (int idx = t; idx < 4096; idx += 256) {
        int c = idx >> 6, n = idx & 63;
        Ts[n][c] = f2bf(xb[(size_t)(c0 + c) * N_TOK + n0 + n]);
    }
    __syncthreads();
    u16* xTb = xT + (size_t)b * N_TOK * C_DIM;
    for (int idx = t; idx < 512; idx += 256) {
        int n = idx >> 3, c8 = idx & 7;
        *(u16x8*)&xTb[(size_t)(n0 + n) * C_DIM + c0 + c8 * 8] =
            *(u16x8*)&Ts[n][c8 * 8];
    }
}

// ---------------------------------------------------------------------------
// Prepass 2: convert weights to bf16 (layouts unchanged).
// ---------------------------------------------------------------------------
__global__ __launch_bounds__(256) void wconv_kernel(
    const float* __restrict__ wq, const float* __restrict__ wk,
    const float* __restrict__ wv, const float* __restrict__ wo,
    u16* __restrict__ wqB, u16* __restrict__ wkB,
    u16* __restrict__ wvB, u16* __restrict__ woB)
{
    const int z = blockIdx.y;
    const float* src = (z == 0) ? wq : (z == 1) ? wk : (z == 2) ? wv : wo;
    u16* dst = (z == 0) ? wqB : (z == 1) ? wkB : (z == 2) ? wvB : woB;
    const int i0 = (blockIdx.x * 256 + threadIdx.x) * 8;
    float4v a = *(const float4v*)&src[i0];
    float4v b = *(const float4v*)&src[i0 + 4];
    u16x8 o;
    o[0] = f2bf(a[0]); o[1] = f2bf(a[1]); o[2] = f2bf(a[2]); o[3] = f2bf(a[3]);
    o[4] = f2bf(b[0]); o[5] = f2bf(b[1]); o[6] = f2bf(b[2]); o[7] = f2bf(b[3]);
    *(u16x8*)&dst[i0] = o;
}

// ---------------------------------------------------------------------------
// Kernel A: q/k/v projections via MFMA. (verified)
// ---------------------------------------------------------------------------
__global__ __launch_bounds__(256) void qkv_gemm_kernel(
    const u16* __restrict__ xT,
    const u16* __restrict__ wqB, const u16* __restrict__ wkB,
    const u16* __restrict__ wvB,
    const float* __restrict__ bq, const float* __restrict__ bk,
    const float* __restrict__ bv,
    u16* __restrict__ qT, u16* __restrict__ kT, u16* __restrict__ vB)
{
    const int n0 = blockIdx.x * 128;
    const int b  = blockIdx.y;
    const int z  = blockIdx.z;
    const u16* wz = (z == 0) ? wqB : (z == 1) ? wkB : wvB;
    const float* bias = (z == 0) ? bq : (z == 1) ? bk : bv;

    const int t  = threadIdx.x;
    const int w  = t >> 6;
    const int l  = t & 63;
    const int lg = l >> 4;
    const int li = l & 15;
    const int cb = w * 32;

    const u16* xTb = xT + (size_t)b * N_TOK * C_DIM;

    const u16* Amat; const u16* Bmat; int arow0, brow0;
    if (z < 2) { Amat = xTb; arow0 = n0; Bmat = wz;  brow0 = 0; }
    else       { Amat = wz;  arow0 = 0;  Bmat = xTb; brow0 = n0; }

    f32x4 acc[8][2];
#pragma unroll
    for (int m = 0; m < 8; ++m)
#pragma unroll
        for (int j = 0; j < 2; ++j)
#pragma unroll
            for (int r = 0; r < 4; ++r) acc[m][j][r] = 0.f;

    const u16* Abase = Amat + (size_t)(arow0 + li) * C_DIM + lg * 8;
    const u16* Bbase = Bmat + (size_t)(brow0 + cb + li) * C_DIM + lg * 8;

#pragma unroll 2
    for (int kk = 0; kk < 16; ++kk) {
        bf16x8 af[8], bfv[2];
#pragma unroll
        for (int m = 0; m < 8; ++m)
            af[m] = *(const bf16x8*)&Abase[(size_t)(m * 16) * C_DIM + kk * 32];
#pragma unroll
        for (int j = 0; j < 2; ++j)
            bfv[j] = *(const bf16x8*)&Bbase[(size_t)(j * 16) * C_DIM + kk * 32];
#pragma unroll
        for (int m = 0; m < 8; ++m)
#pragma unroll
            for (int j = 0; j < 2; ++j)
                acc[m][j] = __builtin_amdgcn_mfma_f32_16x16x32_bf16(
                    af[m], bfv[j], acc[m][j], 0, 0, 0);
    }

    if (z < 2) {
        u16* dst = ((z == 0) ? qT : kT) + (size_t)b * N_TOK * CI_DIM;
#pragma unroll
        for (int j = 0; j < 2; ++j) {
            float bia = bias[cb + j * 16 + li];
#pragma unroll
            for (int m = 0; m < 8; ++m)
#pragma unroll
                for (int r = 0; r < 4; ++r)
                    dst[(size_t)(n0 + m * 16 + lg * 4 + r) * CI_DIM + cb + j * 16 + li] =
                        f2bf(acc[m][j][r] + bia);
        }
    } else {
        u16* dst = vB + (size_t)b * CI_DIM * N_TOK;
#pragma unroll
        for (int m = 0; m < 8; ++m)
#pragma unroll
            for (int r = 0; r < 4; ++r) {
                int o = m * 16 + lg * 4 + r;
                float bia = bias[o];
#pragma unroll
                for (int j = 0; j < 2; ++j)
                    dst[(size_t)o * N_TOK + n0 + cb + j * 16 + li] =
                        f2bf(acc[m][j][r] + bia);
            }
    }
}

// ---------------------------------------------------------------------------
// Kernel B: wave-autonomous MFMA flash attention, KV split 4 ways.
// Round-9 verified structure. ONE change: #pragma unroll 1 on the main loop
// (I$ test — body fits instruction cache instead of streaming ~25KB/iter).
// grid = 512 blocks 1-D; x = combo + 16*qb; combo = b + 4*kvh.
// ---------------------------------------------------------------------------
__global__ __launch_bounds__(256) void attn_mfma_kernel(
    const u16* __restrict__ qT,   // [B][N][CI]
    const u16* __restrict__ kT,   // [B][N][CI]
    const u16* __restrict__ vB,   // [B][CI][N]
    u16* __restrict__ Opart,      // [4][B][N][CI] bf16, unnormalized
    float* __restrict__ Mout,     // [4][B][N]
    float* __restrict__ Lout)     // [4][B][N]
{
    const int x   = blockIdx.x;
    const int qb  = x >> 4;         // [0,32)
    const int b   = x & 3;          // combo = x & 15 -> same XCD per combo
    const int kvh = (x >> 2) & 3;
    const int j_beg = kvh * (N_TOK / KVSPLIT);

    __shared__ u16 Ps[4][32][72];   // per-wave P tile (padded)

    const int t  = threadIdx.x;
    const int w  = t >> 6;
    const int l  = t & 63;
    const int lg = l >> 4;
    const int li = l & 15;
    const int qw = qb * 128 + w * 32;   // this wave's first query row

    const u16* qTb = qT + (size_t)b * N_TOK * CI_DIM;
    const u16* kTb = kT + (size_t)b * N_TOK * CI_DIM;
    const u16* vBb = vB + (size_t)b * CI_DIM * N_TOK;

    // Q fragments direct from global (once)
    bf16x8 qf[2][4];
#pragma unroll
    for (int qt = 0; qt < 2; ++qt)
#pragma unroll
        for (int kc = 0; kc < 4; ++kc)
            qf[qt][kc] = *(const bf16x8*)&qTb[(size_t)(qw + qt * 16 + li) * CI_DIM + kc * 32 + lg * 8];

    f32x4 Oacc[2][8];
#pragma unroll
    for (int qt = 0; qt < 2; ++qt)
#pragma unroll
        for (int ct = 0; ct < 8; ++ct)
#pragma unroll
            for (int r = 0; r < 4; ++r) Oacc[qt][ct][r] = 0.f;

    float mrun[2] = {-1e30f, -1e30f};
    float lrun[2] = {0.f, 0.f};     // per-lane partials (this lane's j's)

#pragma unroll 1
    for (int it = 0; it < N_TOK / KVSPLIT / 64; ++it) {
        const int j0 = j_beg + it * 64;

        // ---- K fragments direct from global (L2-resident per XCD)
        bf16x8 ak[4][4];
#pragma unroll
        for (int jt = 0; jt < 4; ++jt)
#pragma unroll
            for (int kc = 0; kc < 4; ++kc)
                ak[jt][kc] = *(const bf16x8*)&kTb[(size_t)(j0 + jt * 16 + li) * CI_DIM + kc * 32 + lg * 8];

        // ---- QK^T (swapped): S^T[j][i]
        f32x4 sacc[2][4];
#pragma unroll
        for (int qt = 0; qt < 2; ++qt)
#pragma unroll
            for (int jt = 0; jt < 4; ++jt)
#pragma unroll
                for (int r = 0; r < 4; ++r) sacc[qt][jt][r] = 0.f;
        __builtin_amdgcn_s_setprio(1);
#pragma unroll
        for (int jt = 0; jt < 4; ++jt)
#pragma unroll
            for (int kc = 0; kc < 4; ++kc) {
                sacc[0][jt] = __builtin_amdgcn_mfma_f32_16x16x32_bf16(ak[jt][kc], qf[0][kc], sacc[0][jt], 0, 0, 0);
                sacc[1][jt] = __builtin_amdgcn_mfma_f32_16x16x32_bf16(ak[jt][kc], qf[1][kc], sacc[1][jt], 0, 0, 0);
            }
        __builtin_amdgcn_s_setprio(0);

        // ---- issue V fragment loads now; latency hides under softmax
        bf16x8 bvf[8][2];
#pragma unroll
        for (int ct = 0; ct < 8; ++ct)
#pragma unroll
            for (int ks = 0; ks < 2; ++ks)
                bvf[ct][ks] = *(const bf16x8*)&vBb[(size_t)(ct * 16 + li) * N_TOK + j0 + ks * 32 + lg * 8];

        // ---- softmax: shuffle-free common path (defer-max, lane-local trigger)
#pragma unroll
        for (int qt = 0; qt < 2; ++qt) {
            float tl = sacc[qt][0][0];
#pragma unroll
            for (int jt = 0; jt < 4; ++jt)
#pragma unroll
                for (int r = 0; r < 4; ++r) tl = fmaxf(tl, sacc[qt][jt][r]);

            if (__any(tl > mrun[qt] + RESCALE_THR)) {
                // rare path: full cross-lane max + rescale
                float tmax = fmaxf(tl, __shfl_xor(tl, 16));
                tmax = fmaxf(tmax, __shfl_xor(tmax, 32));
                float mold = mrun[qt];
                float mnew = fmaxf(mold, tmax);
                float scale = __expf(mold - mnew);
                lrun[qt] *= scale;
                mrun[qt] = mnew;
#pragma unroll
                for (int r = 0; r < 4; ++r) {
                    float sc_r = __shfl(scale, lg * 4 + r);
#pragma unroll
                    for (int ct = 0; ct < 8; ++ct) Oacc[qt][ct][r] *= sc_r;
                }
            }
            float m = mrun[qt];
            float psum = 0.f;
#pragma unroll
            for (int jt = 0; jt < 4; ++jt) {
                float p0 = __expf(sacc[qt][jt][0] - m);
                float p1 = __expf(sacc[qt][jt][1] - m);
                float p2 = __expf(sacc[qt][jt][2] - m);
                float p3 = __expf(sacc[qt][jt][3] - m);
                psum += (p0 + p1) + (p2 + p3);
                u32 lo = cvt_pk_bf16(p0, p1);
                u32 hi = cvt_pk_bf16(p2, p3);
                u64 pk = (u64)lo | ((u64)hi << 32);
                *(u64a*)&Ps[w][qt * 16 + li][jt * 16 + lg * 4] = pk;
            }
            lrun[qt] += psum;       // per-lane partial; reduced in epilogue
        }

        // order P stores before PV reads (schedule safety under unroll 1)
        asm volatile("" ::: "memory");

        // ---- PV: O^T[i][c] += P[i][j] * V^T[j][c]
        __builtin_amdgcn_s_setprio(1);
#pragma unroll
        for (int ks = 0; ks < 2; ++ks) {
            bf16x8 ap0 = *(const bf16x8a*)&Ps[w][li][ks * 32 + lg * 8];
            bf16x8 ap1 = *(const bf16x8a*)&Ps[w][16 + li][ks * 32 + lg * 8];
#pragma unroll
            for (int ct = 0; ct < 8; ++ct) {
                Oacc[0][ct] = __builtin_amdgcn_mfma_f32_16x16x32_bf16(ap0, bvf[ct][ks], Oacc[0][ct], 0, 0, 0);
                Oacc[1][ct] = __builtin_amdgcn_mfma_f32_16x16x32_bf16(ap1, bvf[ct][ks], Oacc[1][ct], 0, 0, 0);
            }
        }
        __builtin_amdgcn_s_setprio(0);
    }

    // ---- epilogue: finish l (cross-lane reduce), write m/l + bf16 O partial
#pragma unroll
    for (int qt = 0; qt < 2; ++qt) {
        lrun[qt] += __shfl_xor(lrun[qt], 16);
        lrun[qt] += __shfl_xor(lrun[qt], 32);
    }
    const size_t mlbase = ((size_t)kvh * B_DIM + b) * N_TOK + qw;
    if (lg == 0) {
#pragma unroll
        for (int qt = 0; qt < 2; ++qt) {
            Mout[mlbase + qt * 16 + li] = mrun[qt];
            Lout[mlbase + qt * 16 + li] = lrun[qt];
        }
    }
    u16* Ob = Opart + mlbase * CI_DIM;
#pragma unroll
    for (int qt = 0; qt < 2; ++qt)
#pragma unroll
        for (int ct = 0; ct < 8; ++ct)
#pragma unroll
            for (int r = 0; r < 4; ++r)
                Ob[(size_t)(qt * 16 + lg * 4 + r) * CI_DIM + ct * 16 + li] =
                    f2bf(Oacc[qt][ct][r]);
}

// ---------------------------------------------------------------------------
// Kernel C: merge the 4 KV-quarter partials -> attnoB bf16 [B][N][CI]
// ---------------------------------------------------------------------------
__global__ __launch_bounds__(256) void attn_merge_kernel(
    const u16* __restrict__ Opart, const float* __restrict__ Mout,
    const float* __restrict__ Lout, u16* __restrict__ attnoB)
{
    const int qb = blockIdx.x;
    const int b  = blockIdx.y;
    const int t  = threadIdx.x;
    const int i  = qb * 64 + (t & 63);
    const int c0 = (t >> 6) * 32;

    size_t ns[KVSPLIT];
    float cs[KVSPLIT];
    float m = -1e30f;
#pragma unroll
    for (int s = 0; s < KVSPLIT; ++s) {
        ns[s] = ((size_t)s * B_DIM + b) * N_TOK + i;
        cs[s] = Mout[ns[s]];
        m = fmaxf(m, cs[s]);
    }
    float den = 0.f;
#pragma unroll
    for (int s = 0; s < KVSPLIT; ++s) {
        cs[s] = __expf(cs[s] - m);
        den += Lout[ns[s]] * cs[s];
    }
    float inv = 1.f / den;
#pragma unroll
    for (int s = 0; s < KVSPLIT; ++s) cs[s] *= inv;

    u16* ab = attnoB + ((size_t)b * N_TOK + i) * CI_DIM;
#pragma unroll
    for (int g = 0; g < 4; ++g) {
        float acc[8];
#pragma unroll
        for (int e = 0; e < 8; ++e) acc[e] = 0.f;
#pragma unroll
        for (int s = 0; s < KVSPLIT; ++s) {
            u16x8 ov = *(const u16x8*)&Opart[ns[s] * CI_DIM + c0 + g * 8];
#pragma unroll
            for (int e = 0; e < 8; ++e) acc[e] += bf2f(ov[e]) * cs[s];
        }
        u16x8 res;
#pragma unroll
        for (int e = 0; e < 8; ++e) res[e] = f2bf(acc[e]);
        *(u16x8*)&ab[c0 + g * 8] = res;
    }
}

// ---------------------------------------------------------------------------
// Kernel D: output projection via MFMA + bias + residual, fp32 out.
// ---------------------------------------------------------------------------
__global__ __launch_bounds__(256) void out_gemm_kernel(
    const u16* __restrict__ attnoB,  // [B][N][CI] bf16
    const u16* __restrict__ woB,     // [C][CI] bf16
    const float* __restrict__ bo,    // [C]
    const float* __restrict__ x,     // [B][C][N]
    float* __restrict__ out)         // [B][C][N]
{
    const int n0 = blockIdx.x * 64;
    const int b  = blockIdx.y;
    const int t  = threadIdx.x;
    const int w  = t >> 6;
    const int l  = t & 63;
    const int lg = l >> 4;
    const int li = l & 15;
    const int co0 = w * 128;

    const u16* ab = attnoB + (size_t)b * N_TOK * CI_DIM;

    f32x4 acc[8][4];
#pragma unroll
    for (int m = 0; m < 8; ++m)
#pragma unroll
        for (int j = 0; j < 4; ++j)
#pragma unroll
            for (int r = 0; r < 4; ++r) acc[m][j][r] = 0.f;

    const u16* Abase = woB + (size_t)(co0 + li) * CI_DIM + lg * 8;
    const u16* Bbase = ab + (size_t)(n0 + li) * CI_DIM + lg * 8;

#pragma unroll
    for (int kk = 0; kk < 4; ++kk) {
        bf16x8 af[8], bfv[4];
#pragma unroll
        for (int m = 0; m < 8; ++m)
            af[m] = *(const bf16x8*)&Abase[(size_t)(m * 16) * CI_DIM + kk * 32];
#pragma unroll
        for (int j = 0; j < 4; ++j)
            bfv[j] = *(const bf16x8*)&Bbase[(size_t)(j * 16) * CI_DIM + kk * 32];
#pragma unroll
        for (int m = 0; m < 8; ++m)
#pragma unroll
            for (int j = 0; j < 4; ++j)
                acc[m][j] = __builtin_amdgcn_mfma_f32_16x16x32_bf16(
                    af[m], bfv[j], acc[m][j], 0, 0, 0);
    }

    const size_t base = (size_t)b * C_DIM * N_TOK;
#pragma unroll
    for (int m = 0; m < 8; ++m)
#pragma unroll
        for (int r = 0; r < 4; ++r) {
            int co = co0 + m * 16 + lg * 4 + r;
            float bia = bo[co];
#pragma unroll
            for (int j = 0; j < 4; ++j) {
                size_t idx = base + (size_t)co * N_TOK + n0 + j * 16 + li;
                out[idx] = acc[m][j][r] + bia + x[idx];
            }
        }
}

extern "C" void kernel_launch(void* const* d_in, const int* in_sizes, int n_in,
                              void* d_out, int out_size, void* d_ws, size_t ws_size,
                              hipStream_t stream) {
    const float* x  = (const float*)d_in[0];
    const float* wq = (const float*)d_in[1];
    const float* bq = (const float*)d_in[2];
    const float* wk = (const float*)d_in[3];
    const float* bk = (const float*)d_in[4];
    const float* wv = (const float*)d_in[5];
    const float* bv = (const float*)d_in[6];
    const float* wo = (const float*)d_in[7];
    const float* bo = (const float*)d_in[8];
    float* out = (float*)d_out;

    // workspace layout (bytes):
    //  [0,16M)         xT bf16 [B][N][C]  -- dead after qkv_gemm; reused as
    //                  Opart bf16 [4][B][N][CI] (exactly 16 MB)
    //  [16M,16.5M)     wqB/wkB/wvB/woB bf16 (128K each)
    //  [16.5M,20.5M)   qT bf16 [B][N][CI]
    //  [20.5M,24.5M)   kT bf16 [B][N][CI]
    //  [24.5M,28.5M)   vB bf16 [B][CI][N]
    //  [28.5M,+512K)   Mout/Lout f32 [4][B][N] (256K each)
    //  [29M,33M)       attnoB bf16 [B][N][CI]
    char* ws = (char*)d_ws;
    const size_t MB = 1024 * 1024;
    u16*   xT    = (u16*)(ws);
    u16*   Opart = (u16*)(ws);                   // aliases xT (16 MB, exact)
    u16*   wqB   = (u16*)(ws + 16 * MB);
    u16*   wkB   = (u16*)(ws + 16 * MB + 128 * 1024);
    u16*   wvB   = (u16*)(ws + 16 * MB + 256 * 1024);
    u16*   woB   = (u16*)(ws + 16 * MB + 384 * 1024);
    u16*   qT    = (u16*)(ws + 16 * MB + 512 * 1024);
    u16*   kT    = (u16*)(ws + 20 * MB + 512 * 1024);
    u16*   vB    = (u16*)(ws + 24 * MB + 512 * 1024);
    float* Mout  = (float*)(ws + 28 * MB + 512 * 1024);
    float* Lout  = (float*)(ws + 28 * MB + 768 * 1024);
    u16*  attnoB = (u16*)(ws + 29 * MB);

    xpose_kernel<<<dim3(64, 8, 4), 256, 0, stream>>>(x, xT);
    wconv_kernel<<<dim3(32, 4), 256, 0, stream>>>(
        wq, wk, wv, wo, wqB, wkB, wvB, woB);
    qkv_gemm_kernel<<<dim3(32, 4, 3), 256, 0, stream>>>(
        xT, wqB, wkB, wvB, bq, bk, bv, qT, kT, vB);
    attn_mfma_kernel<<<dim3(512), 256, 0, stream>>>(
        qT, kT, vB, Opart, Mout, Lout);
    attn_merge_kernel<<<dim3(64, 4), 256, 0, stream>>>(
        Opart, Mout, Lout, attnoB);
    out_gemm_kernel<<<dim3(64, 4), 256, 0, stream>>>(
        attnoB, woB, bo, x, out);
}

// Round 11
// 134.607 us; speedup vs baseline: 1.4617x; 1.4617x over previous
//
#include <hip/hip_runtime.h>

#define N_TOK 4096
#define C_DIM 512
#define CI_DIM 128
#define B_DIM 4
#define KVSPLIT 4
#define KVBLK 32
#define NIT (N_TOK / KVSPLIT / KVBLK)
#define RESCALE_THR 8.0f

typedef unsigned short u16;
typedef unsigned int u32;
typedef unsigned long long u64;
typedef __attribute__((ext_vector_type(8))) short bf16x8;
typedef __attribute__((ext_vector_type(4))) float f32x4;
typedef __attribute__((ext_vector_type(8))) unsigned short u16x8;
typedef __attribute__((ext_vector_type(4))) float float4v;

// alias-safe views of the P tile (stored as u64, read back as bf16x8)
typedef unsigned long long __attribute__((may_alias)) u64a;
typedef bf16x8 __attribute__((may_alias)) bf16x8a;
typedef u16x8 __attribute__((may_alias)) u16x8a;

__device__ __forceinline__ u16 f2bf(float f) {
    union { float f; u32 u; } v; v.f = f;
    u32 r = (v.u + 0x7fffu + ((v.u >> 16) & 1u)) >> 16;
    return (u16)r;
}
__device__ __forceinline__ float bf2f(u16 h) {
    union { u32 u; float f; } v; v.u = (u32)h << 16;
    return v.f;
}
__device__ __forceinline__ u32 cvt_pk_bf16(float a, float b) {
    u32 r;
    asm("v_cvt_pk_bf16_f32 %0, %1, %2" : "=v"(r) : "v"(a), "v"(b));
    return r;
}

// ---------------------------------------------------------------------------
// Prepass 1: transpose+convert x f32 [B][C][N] -> xT bf16 [B][N][C]
// ---------------------------------------------------------------------------
__global__ __launch_bounds__(256) void xpose_kernel(
    const float* __restrict__ x, u16* __restrict__ xT)
{
    const int n0 = blockIdx.x * 64;
    const int c0 = blockIdx.y * 64;
    const int b  = blockIdx.z;
    __shared__ u16 Ts[64][72];
    const int t = threadIdx.x;

    const float* xb = x + (size_t)b * C_DIM * N_TOK;
    for (int idx = t; idx < 4096; idx += 256) {
        int c = idx >> 6, n = idx & 63;
        Ts[n][c] = f2bf(xb[(size_t)(c0 + c) * N_TOK + n0 + n]);
    }
    __syncthreads();
    u16* xTb = xT + (size_t)b * N_TOK * C_DIM;
    for (int idx = t; idx < 512; idx += 256) {
        int n = idx >> 3, c8 = idx & 7;
        *(u16x8*)&xTb[(size_t)(n0 + n) * C_DIM + c0 + c8 * 8] =
            *(u16x8*)&Ts[n][c8 * 8];
    }
}

// ---------------------------------------------------------------------------
// Prepass 2: convert weights to bf16 (layouts unchanged).
// ---------------------------------------------------------------------------
__global__ __launch_bounds__(256) void wconv_kernel(
    const float* __restrict__ wq, const float* __restrict__ wk,
    const float* __restrict__ wv, const float* __restrict__ wo,
    u16* __restrict__ wqB, u16* __restrict__ wkB,
    u16* __restrict__ wvB, u16* __restrict__ woB)
{
    const int z = blockIdx.y;
    const float* src = (z == 0) ? wq : (z == 1) ? wk : (z == 2) ? wv : wo;
    u16* dst = (z == 0) ? wqB : (z == 1) ? wkB : (z == 2) ? wvB : woB;
    const int i0 = (blockIdx.x * 256 + threadIdx.x) * 8;
    float4v a = *(const float4v*)&src[i0];
    float4v b = *(const float4v*)&src[i0 + 4];
    u16x8 o;
    o[0] = f2bf(a[0]); o[1] = f2bf(a[1]); o[2] = f2bf(a[2]); o[3] = f2bf(a[3]);
    o[4] = f2bf(b[0]); o[5] = f2bf(b[1]); o[6] = f2bf(b[2]); o[7] = f2bf(b[3]);
    *(u16x8*)&dst[i0] = o;
}

// ---------------------------------------------------------------------------
// Kernel A: q/k/v projections via MFMA. (verified)
// ---------------------------------------------------------------------------
__global__ __launch_bounds__(256) void qkv_gemm_kernel(
    const u16* __restrict__ xT,
    const u16* __restrict__ wqB, const u16* __restrict__ wkB,
    const u16* __restrict__ wvB,
    const float* __restrict__ bq, const float* __restrict__ bk,
    const float* __restrict__ bv,
    u16* __restrict__ qT, u16* __restrict__ kT, u16* __restrict__ vB)
{
    const int n0 = blockIdx.x * 128;
    const int b  = blockIdx.y;
    const int z  = blockIdx.z;
    const u16* wz = (z == 0) ? wqB : (z == 1) ? wkB : wvB;
    const float* bias = (z == 0) ? bq : (z == 1) ? bk : bv;

    const int t  = threadIdx.x;
    const int w  = t >> 6;
    const int l  = t & 63;
    const int lg = l >> 4;
    const int li = l & 15;
    const int cb = w * 32;

    const u16* xTb = xT + (size_t)b * N_TOK * C_DIM;

    const u16* Amat; const u16* Bmat; int arow0, brow0;
    if (z < 2) { Amat = xTb; arow0 = n0; Bmat = wz;  brow0 = 0; }
    else       { Amat = wz;  arow0 = 0;  Bmat = xTb; brow0 = n0; }

    f32x4 acc[8][2];
#pragma unroll
    for (int m = 0; m < 8; ++m)
#pragma unroll
        for (int j = 0; j < 2; ++j)
#pragma unroll
            for (int r = 0; r < 4; ++r) acc[m][j][r] = 0.f;

    const u16* Abase = Amat + (size_t)(arow0 + li) * C_DIM + lg * 8;
    const u16* Bbase = Bmat + (size_t)(brow0 + cb + li) * C_DIM + lg * 8;

#pragma unroll 2
    for (int kk = 0; kk < 16; ++kk) {
        bf16x8 af[8], bfv[2];
#pragma unroll
        for (int m = 0; m < 8; ++m)
            af[m] = *(const bf16x8*)&Abase[(size_t)(m * 16) * C_DIM + kk * 32];
#pragma unroll
        for (int j = 0; j < 2; ++j)
            bfv[j] = *(const bf16x8*)&Bbase[(size_t)(j * 16) * C_DIM + kk * 32];
#pragma unroll
        for (int m = 0; m < 8; ++m)
#pragma unroll
            for (int j = 0; j < 2; ++j)
                acc[m][j] = __builtin_amdgcn_mfma_f32_16x16x32_bf16(
                    af[m], bfv[j], acc[m][j], 0, 0, 0);
    }

    if (z < 2) {
        u16* dst = ((z == 0) ? qT : kT) + (size_t)b * N_TOK * CI_DIM;
#pragma unroll
        for (int j = 0; j < 2; ++j) {
            float bia = bias[cb + j * 16 + li];
#pragma unroll
            for (int m = 0; m < 8; ++m)
#pragma unroll
                for (int r = 0; r < 4; ++r)
                    dst[(size_t)(n0 + m * 16 + lg * 4 + r) * CI_DIM + cb + j * 16 + li] =
                        f2bf(acc[m][j][r] + bia);
        }
    } else {
        u16* dst = vB + (size_t)b * CI_DIM * N_TOK;
#pragma unroll
        for (int m = 0; m < 8; ++m)
#pragma unroll
            for (int r = 0; r < 4; ++r) {
                int o = m * 16 + lg * 4 + r;
                float bia = bias[o];
#pragma unroll
                for (int j = 0; j < 2; ++j)
                    dst[(size_t)o * N_TOK + n0 + cb + j * 16 + li] =
                        f2bf(acc[m][j][r] + bia);
            }
    }
}

// ---------------------------------------------------------------------------
// Kernel B: MFMA flash attention, KV split 4 ways, LDS-staged K/V tiles.
// KVBLK=32: K tile [32][144] (9.2KB), V tile [128][48] (12.3KB),
// Ps [4][32][32] (8KB) -> 29.7KB total, 2 blocks/CU.
// Staging: coalesced global->reg prefetch of tile t+1 issued right after the
// barrier (T14 async-split: latency hides under compute of tile t), ds_write
// at top of next iteration. Fragment reads are ds_read_b128 (no more
// 16-line-scattered global loads - the r4..r10 latency wall).
// grid = 512 blocks 1-D; x = combo + 16*qb; combo = b + 4*kvh (XCD swizzle).
// ---------------------------------------------------------------------------
__global__ __launch_bounds__(256) void attn_mfma_kernel(
    const u16* __restrict__ qT,   // [B][N][CI]
    const u16* __restrict__ kT,   // [B][N][CI]
    const u16* __restrict__ vB,   // [B][CI][N]
    u16* __restrict__ Opart,      // [4][B][N][CI] bf16, unnormalized
    float* __restrict__ Mout,     // [4][B][N]
    float* __restrict__ Lout)     // [4][B][N]
{
    const int x   = blockIdx.x;
    const int qb  = x >> 4;         // [0,32)
    const int b   = x & 3;          // combo = x & 15 -> same XCD per combo
    const int kvh = (x >> 2) & 3;
    const int j_beg = kvh * (N_TOK / KVSPLIT);

    __shared__ u16 Ks[KVBLK][144];   // K tile, token-major (padded, 16B rows)
    __shared__ u16 Vs[CI_DIM][48];   // V tile, channel-major (padded)
    __shared__ u16 Ps[4][32][32];    // per-wave P tile (exact rows)

    const int t  = threadIdx.x;
    const int w  = t >> 6;
    const int l  = t & 63;
    const int lg = l >> 4;
    const int li = l & 15;
    const int qw = qb * 128 + w * 32;   // this wave's first query row

    // staging coordinates (coalesced global reads)
    const int krow = t >> 3, kc8 = t & 7;    // K: 32 rows x 8 chunks of 16 u16
    const int vch  = t >> 1, vh  = t & 1;    // V: 128 ch x 2 chunks of 16 u16

    const u16* qTb = qT + (size_t)b * N_TOK * CI_DIM;
    const u16* kTb = kT + (size_t)b * N_TOK * CI_DIM;
    const u16* vBb = vB + (size_t)b * CI_DIM * N_TOK;

    // Q fragments direct from global (once)
    bf16x8 qf[2][4];
#pragma unroll
    for (int qt = 0; qt < 2; ++qt)
#pragma unroll
        for (int kc = 0; kc < 4; ++kc)
            qf[qt][kc] = *(const bf16x8*)&qTb[(size_t)(qw + qt * 16 + li) * CI_DIM + kc * 32 + lg * 8];

    f32x4 Oacc[2][8];
#pragma unroll
    for (int qt = 0; qt < 2; ++qt)
#pragma unroll
        for (int ct = 0; ct < 8; ++ct)
#pragma unroll
            for (int r = 0; r < 4; ++r) Oacc[qt][ct][r] = 0.f;

    float mrun[2] = {-1e30f, -1e30f};
    float lrun[2] = {0.f, 0.f};     // per-lane partials

    // prologue: prefetch tile 0 into regs
    u16x8 kv0, kv1, vv0, vv1;
    {
        const u16* ksrc = &kTb[(size_t)(j_beg + krow) * CI_DIM + kc8 * 16];
        kv0 = *(const u16x8a*)&ksrc[0];
        kv1 = *(const u16x8a*)&ksrc[8];
        const u16* vsrc = &vBb[(size_t)vch * N_TOK + j_beg + vh * 16];
        vv0 = *(const u16x8a*)&vsrc[0];
        vv1 = *(const u16x8a*)&vsrc[8];
    }

#pragma unroll 1
    for (int it = 0; it < NIT; ++it) {
        // (A) all waves done reading previous tile
        __syncthreads();
        *(u16x8a*)&Ks[krow][kc8 * 16]     = kv0;
        *(u16x8a*)&Ks[krow][kc8 * 16 + 8] = kv1;
        *(u16x8a*)&Vs[vch][vh * 16]       = vv0;
        *(u16x8a*)&Vs[vch][vh * 16 + 8]   = vv1;
        // (B) tile ready
        __syncthreads();

        // prefetch next tile into regs; latency hides under compute below
        if (it + 1 < NIT) {
            const int jn = j_beg + (it + 1) * KVBLK;
            const u16* ksrc = &kTb[(size_t)(jn + krow) * CI_DIM + kc8 * 16];
            kv0 = *(const u16x8a*)&ksrc[0];
            kv1 = *(const u16x8a*)&ksrc[8];
            const u16* vsrc = &vBb[(size_t)vch * N_TOK + jn + vh * 16];
            vv0 = *(const u16x8a*)&vsrc[0];
            vv1 = *(const u16x8a*)&vsrc[8];
        }

        // ---- QK^T (swapped): S^T[j][i], fragments from LDS
        bf16x8 ak[2][4];
#pragma unroll
        for (int jt = 0; jt < 2; ++jt)
#pragma unroll
            for (int kc = 0; kc < 4; ++kc)
                ak[jt][kc] = *(const bf16x8a*)&Ks[jt * 16 + li][kc * 32 + lg * 8];

        f32x4 sacc[2][2];
#pragma unroll
        for (int qt = 0; qt < 2; ++qt)
#pragma unroll
            for (int jt = 0; jt < 2; ++jt)
#pragma unroll
                for (int r = 0; r < 4; ++r) sacc[qt][jt][r] = 0.f;
        __builtin_amdgcn_s_setprio(1);
#pragma unroll
        for (int jt = 0; jt < 2; ++jt)
#pragma unroll
            for (int kc = 0; kc < 4; ++kc) {
                sacc[0][jt] = __builtin_amdgcn_mfma_f32_16x16x32_bf16(ak[jt][kc], qf[0][kc], sacc[0][jt], 0, 0, 0);
                sacc[1][jt] = __builtin_amdgcn_mfma_f32_16x16x32_bf16(ak[jt][kc], qf[1][kc], sacc[1][jt], 0, 0, 0);
            }
        __builtin_amdgcn_s_setprio(0);

        // ---- softmax: shuffle-free common path (defer-max)
#pragma unroll
        for (int qt = 0; qt < 2; ++qt) {
            float tl = sacc[qt][0][0];
#pragma unroll
            for (int jt = 0; jt < 2; ++jt)
#pragma unroll
                for (int r = 0; r < 4; ++r) tl = fmaxf(tl, sacc[qt][jt][r]);

            if (__any(tl > mrun[qt] + RESCALE_THR)) {
                float tmax = fmaxf(tl, __shfl_xor(tl, 16));
                tmax = fmaxf(tmax, __shfl_xor(tmax, 32));
                float mold = mrun[qt];
                float mnew = fmaxf(mold, tmax);
                float scale = __expf(mold - mnew);
                lrun[qt] *= scale;
                mrun[qt] = mnew;
#pragma unroll
                for (int r = 0; r < 4; ++r) {
                    float sc_r = __shfl(scale, lg * 4 + r);
#pragma unroll
                    for (int ct = 0; ct < 8; ++ct) Oacc[qt][ct][r] *= sc_r;
                }
            }
            float m = mrun[qt];
            float psum = 0.f;
#pragma unroll
            for (int jt = 0; jt < 2; ++jt) {
                float p0 = __expf(sacc[qt][jt][0] - m);
                float p1 = __expf(sacc[qt][jt][1] - m);
                float p2 = __expf(sacc[qt][jt][2] - m);
                float p3 = __expf(sacc[qt][jt][3] - m);
                psum += (p0 + p1) + (p2 + p3);
                u32 lo = cvt_pk_bf16(p0, p1);
                u32 hi = cvt_pk_bf16(p2, p3);
                u64 pk = (u64)lo | ((u64)hi << 32);
                *(u64a*)&Ps[w][qt * 16 + li][jt * 16 + lg * 4] = pk;
            }
            lrun[qt] += psum;
        }

        // order P stores before PV reads
        asm volatile("" ::: "memory");

        // ---- PV: O^T[i][c] += P[i][j] * V^T[j][c]  (K=32, one slice)
        bf16x8 ap0 = *(const bf16x8a*)&Ps[w][li][lg * 8];
        bf16x8 ap1 = *(const bf16x8a*)&Ps[w][16 + li][lg * 8];
        __builtin_amdgcn_s_setprio(1);
#pragma unroll
        for (int ct = 0; ct < 8; ++ct) {
            bf16x8 bv = *(const bf16x8a*)&Vs[ct * 16 + li][lg * 8];
            Oacc[0][ct] = __builtin_amdgcn_mfma_f32_16x16x32_bf16(ap0, bv, Oacc[0][ct], 0, 0, 0);
            Oacc[1][ct] = __builtin_amdgcn_mfma_f32_16x16x32_bf16(ap1, bv, Oacc[1][ct], 0, 0, 0);
        }
        __builtin_amdgcn_s_setprio(0);
    }

    // ---- epilogue: finish l (cross-lane reduce), write m/l + bf16 O partial
#pragma unroll
    for (int qt = 0; qt < 2; ++qt) {
        lrun[qt] += __shfl_xor(lrun[qt], 16);
        lrun[qt] += __shfl_xor(lrun[qt], 32);
    }
    const size_t mlbase = ((size_t)kvh * B_DIM + b) * N_TOK + qw;
    if (lg == 0) {
#pragma unroll
        for (int qt = 0; qt < 2; ++qt) {
            Mout[mlbase + qt * 16 + li] = mrun[qt];
            Lout[mlbase + qt * 16 + li] = lrun[qt];
        }
    }
    u16* Ob = Opart + mlbase * CI_DIM;
#pragma unroll
    for (int qt = 0; qt < 2; ++qt)
#pragma unroll
        for (int ct = 0; ct < 8; ++ct)
#pragma unroll
            for (int r = 0; r < 4; ++r)
                Ob[(size_t)(qt * 16 + lg * 4 + r) * CI_DIM + ct * 16 + li] =
                    f2bf(Oacc[qt][ct][r]);
}

// ---------------------------------------------------------------------------
// Kernel C: merge the 4 KV-quarter partials -> attnoB bf16 [B][N][CI]
// ---------------------------------------------------------------------------
__global__ __launch_bounds__(256) void attn_merge_kernel(
    const u16* __restrict__ Opart, const float* __restrict__ Mout,
    const float* __restrict__ Lout, u16* __restrict__ attnoB)
{
    const int qb = blockIdx.x;
    const int b  = blockIdx.y;
    const int t  = threadIdx.x;
    const int i  = qb * 64 + (t & 63);
    const int c0 = (t >> 6) * 32;

    size_t ns[KVSPLIT];
    float cs[KVSPLIT];
    float m = -1e30f;
#pragma unroll
    for (int s = 0; s < KVSPLIT; ++s) {
        ns[s] = ((size_t)s * B_DIM + b) * N_TOK + i;
        cs[s] = Mout[ns[s]];
        m = fmaxf(m, cs[s]);
    }
    float den = 0.f;
#pragma unroll
    for (int s = 0; s < KVSPLIT; ++s) {
        cs[s] = __expf(cs[s] - m);
        den += Lout[ns[s]] * cs[s];
    }
    float inv = 1.f / den;
#pragma unroll
    for (int s = 0; s < KVSPLIT; ++s) cs[s] *= inv;

    u16* ab = attnoB + ((size_t)b * N_TOK + i) * CI_DIM;
#pragma unroll
    for (int g = 0; g < 4; ++g) {
        float acc[8];
#pragma unroll
        for (int e = 0; e < 8; ++e) acc[e] = 0.f;
#pragma unroll
        for (int s = 0; s < KVSPLIT; ++s) {
            u16x8 ov = *(const u16x8*)&Opart[ns[s] * CI_DIM + c0 + g * 8];
#pragma unroll
            for (int e = 0; e < 8; ++e) acc[e] += bf2f(ov[e]) * cs[s];
        }
        u16x8 res;
#pragma unroll
        for (int e = 0; e < 8; ++e) res[e] = f2bf(acc[e]);
        *(u16x8*)&ab[c0 + g * 8] = res;
    }
}

// ---------------------------------------------------------------------------
// Kernel D: output projection via MFMA + bias + residual, fp32 out.
// ---------------------------------------------------------------------------
__global__ __launch_bounds__(256) void out_gemm_kernel(
    const u16* __restrict__ attnoB,  // [B][N][CI] bf16
    const u16* __restrict__ woB,     // [C][CI] bf16
    const float* __restrict__ bo,    // [C]
    const float* __restrict__ x,     // [B][C][N]
    float* __restrict__ out)         // [B][C][N]
{
    const int n0 = blockIdx.x * 64;
    const int b  = blockIdx.y;
    const int t  = threadIdx.x;
    const int w  = t >> 6;
    const int l  = t & 63;
    const int lg = l >> 4;
    const int li = l & 15;
    const int co0 = w * 128;

    const u16* ab = attnoB + (size_t)b * N_TOK * CI_DIM;

    f32x4 acc[8][4];
#pragma unroll
    for (int m = 0; m < 8; ++m)
#pragma unroll
        for (int j = 0; j < 4; ++j)
#pragma unroll
            for (int r = 0; r < 4; ++r) acc[m][j][r] = 0.f;

    const u16* Abase = woB + (size_t)(co0 + li) * CI_DIM + lg * 8;
    const u16* Bbase = ab + (size_t)(n0 + li) * CI_DIM + lg * 8;

#pragma unroll
    for (int kk = 0; kk < 4; ++kk) {
        bf16x8 af[8], bfv[4];
#pragma unroll
        for (int m = 0; m < 8; ++m)
            af[m] = *(const bf16x8*)&Abase[(size_t)(m * 16) * CI_DIM + kk * 32];
#pragma unroll
        for (int j = 0; j < 4; ++j)
            bfv[j] = *(const bf16x8*)&Bbase[(size_t)(j * 16) * CI_DIM + kk * 32];
#pragma unroll
        for (int m = 0; m < 8; ++m)
#pragma unroll
            for (int j = 0; j < 4; ++j)
                acc[m][j] = __builtin_amdgcn_mfma_f32_16x16x32_bf16(
                    af[m], bfv[j], acc[m][j], 0, 0, 0);
    }

    const size_t base = (size_t)b * C_DIM * N_TOK;
#pragma unroll
    for (int m = 0; m < 8; ++m)
#pragma unroll
        for (int r = 0; r < 4; ++r) {
            int co = co0 + m * 16 + lg * 4 + r;
            float bia = bo[co];
#pragma unroll
            for (int j = 0; j < 4; ++j) {
                size_t idx = base + (size_t)co * N_TOK + n0 + j * 16 + li;
                out[idx] = acc[m][j][r] + bia + x[idx];
            }
        }
}

extern "C" void kernel_launch(void* const* d_in, const int* in_sizes, int n_in,
                              void* d_out, int out_size, void* d_ws, size_t ws_size,
                              hipStream_t stream) {
    const float* x  = (const float*)d_in[0];
    const float* wq = (const float*)d_in[1];
    const float* bq = (const float*)d_in[2];
    const float* wk = (const float*)d_in[3];
    const float* bk = (const float*)d_in[4];
    const float* wv = (const float*)d_in[5];
    const float* bv = (const float*)d_in[6];
    const float* wo = (const float*)d_in[7];
    const float* bo = (const float*)d_in[8];
    float* out = (float*)d_out;

    // workspace layout (bytes):
    //  [0,16M)         xT bf16 [B][N][C]  -- dead after qkv_gemm; reused as
    //                  Opart bf16 [4][B][N][CI] (exactly 16 MB)
    //  [16M,16.5M)     wqB/wkB/wvB/woB bf16 (128K each)
    //  [16.5M,20.5M)   qT bf16 [B][N][CI]
    //  [20.5M,24.5M)   kT bf16 [B][N][CI]
    //  [24.5M,28.5M)   vB bf16 [B][CI][N]
    //  [28.5M,+512K)   Mout/Lout f32 [4][B][N] (256K each)
    //  [29M,33M)       attnoB bf16 [B][N][CI]
    char* ws = (char*)d_ws;
    const size_t MB = 1024 * 1024;
    u16*   xT    = (u16*)(ws);
    u16*   Opart = (u16*)(ws);                   // aliases xT (16 MB, exact)
    u16*   wqB   = (u16*)(ws + 16 * MB);
    u16*   wkB   = (u16*)(ws + 16 * MB + 128 * 1024);
    u16*   wvB   = (u16*)(ws + 16 * MB + 256 * 1024);
    u16*   woB   = (u16*)(ws + 16 * MB + 384 * 1024);
    u16*   qT    = (u16*)(ws + 16 * MB + 512 * 1024);
    u16*   kT    = (u16*)(ws + 20 * MB + 512 * 1024);
    u16*   vB    = (u16*)(ws + 24 * MB + 512 * 1024);
    float* Mout  = (float*)(ws + 28 * MB + 512 * 1024);
    float* Lout  = (float*)(ws + 28 * MB + 768 * 1024);
    u16*  attnoB = (u16*)(ws + 29 * MB);

    xpose_kernel<<<dim3(64, 8, 4), 256, 0, stream>>>(x, xT);
    wconv_kernel<<<dim3(32, 4), 256, 0, stream>>>(
        wq, wk, wv, wo, wqB, wkB, wvB, woB);
    qkv_gemm_kernel<<<dim3(32, 4, 3), 256, 0, stream>>>(
        xT, wqB, wkB, wvB, bq, bk, bv, qT, kT, vB);
    attn_mfma_kernel<<<dim3(512), 256, 0, stream>>>(
        qT, kT, vB, Opart, Mout, Lout);
    attn_merge_kernel<<<dim3(64, 4), 256, 0, stream>>>(
        Opart, Mout, Lout, attnoB);
    out_gemm_kernel<<<dim3(64, 4), 256, 0, stream>>>(
        attnoB, woB, bo, x, out);
}

// Round 12
// 107.133 us; speedup vs baseline: 1.8366x; 1.2564x over previous
//
#include <hip/hip_runtime.h>

#define N_TOK 4096
#define C_DIM 512
#define CI_DIM 128
#define B_DIM 4
#define KVSPLIT 4
#define KVBLK 32
#define NIT (N_TOK / KVSPLIT / KVBLK)
#define RESCALE_THR 8.0f

typedef unsigned short u16;
typedef unsigned int u32;
typedef unsigned long long u64;
typedef __attribute__((ext_vector_type(8))) short bf16x8;
typedef __attribute__((ext_vector_type(4))) float f32x4;
typedef __attribute__((ext_vector_type(8))) unsigned short u16x8;
typedef __attribute__((ext_vector_type(4))) float float4v;

// alias-safe views of LDS tiles (stored via one type, read via another)
typedef unsigned long long __attribute__((may_alias)) u64a;
typedef bf16x8 __attribute__((may_alias)) bf16x8a;
typedef u16x8 __attribute__((may_alias)) u16x8a;

__device__ __forceinline__ u16 f2bf(float f) {
    union { float f; u32 u; } v; v.f = f;
    u32 r = (v.u + 0x7fffu + ((v.u >> 16) & 1u)) >> 16;
    return (u16)r;
}
__device__ __forceinline__ float bf2f(u16 h) {
    union { u32 u; float f; } v; v.u = (u32)h << 16;
    return v.f;
}
__device__ __forceinline__ u32 cvt_pk_bf16(float a, float b) {
    u32 r;
    asm("v_cvt_pk_bf16_f32 %0, %1, %2" : "=v"(r) : "v"(a), "v"(b));
    return r;
}

// ---------------------------------------------------------------------------
// Prepass 1: transpose+convert x f32 [B][C][N] -> xT bf16 [B][N][C]
// ---------------------------------------------------------------------------
__global__ __launch_bounds__(256) void xpose_kernel(
    const float* __restrict__ x, u16* __restrict__ xT)
{
    const int n0 = blockIdx.x * 64;
    const int c0 = blockIdx.y * 64;
    const int b  = blockIdx.z;
    __shared__ u16 Ts[64][72];
    const int t = threadIdx.x;

    const float* xb = x + (size_t)b * C_DIM * N_TOK;
    for (int idx = t; idx < 4096; idx += 256) {
        int c = idx >> 6, n = idx & 63;
        Ts[n][c] = f2bf(xb[(size_t)(c0 + c) * N_TOK + n0 + n]);
    }
    __syncthreads();
    u16* xTb = xT + (size_t)b * N_TOK * C_DIM;
    for (int idx = t; idx < 512; idx += 256) {
        int n = idx >> 3, c8 = idx & 7;
        *(u16x8*)&xTb[(size_t)(n0 + n) * C_DIM + c0 + c8 * 8] =
            *(u16x8*)&Ts[n][c8 * 8];
    }
}

// ---------------------------------------------------------------------------
// Prepass 2: convert weights to bf16 (layouts unchanged).
// ---------------------------------------------------------------------------
__global__ __launch_bounds__(256) void wconv_kernel(
    const float* __restrict__ wq, const float* __restrict__ wk,
    const float* __restrict__ wv, const float* __restrict__ wo,
    u16* __restrict__ wqB, u16* __restrict__ wkB,
    u16* __restrict__ wvB, u16* __restrict__ woB)
{
    const int z = blockIdx.y;
    const float* src = (z == 0) ? wq : (z == 1) ? wk : (z == 2) ? wv : wo;
    u16* dst = (z == 0) ? wqB : (z == 1) ? wkB : (z == 2) ? wvB : woB;
    const int i0 = (blockIdx.x * 256 + threadIdx.x) * 8;
    float4v a = *(const float4v*)&src[i0];
    float4v b = *(const float4v*)&src[i0 + 4];
    u16x8 o;
    o[0] = f2bf(a[0]); o[1] = f2bf(a[1]); o[2] = f2bf(a[2]); o[3] = f2bf(a[3]);
    o[4] = f2bf(b[0]); o[5] = f2bf(b[1]); o[6] = f2bf(b[2]); o[7] = f2bf(b[3]);
    *(u16x8*)&dst[i0] = o;
}

// ---------------------------------------------------------------------------
// Kernel A: q/k/v projections via MFMA, LDS-staged operand tiles (r11
// template): Xs = xT rows n0..n0+127, Ws = w rows 0..127, per 64-K chunk.
// Reg-prefetch of chunk k+1 issued right after the barrier (T14). Fragments
// via ds_read_b128 from conflict-free [.][72] rows (144B = 9 quads).
// z<2: A=Xs (tokens), B=Ws; z=2: A=Ws, B=Xs (pure LDS-pointer swap).
// grid = (32 n-tiles of 128, B, 3), block = 256.
// ---------------------------------------------------------------------------
__global__ __launch_bounds__(256) void qkv_gemm_kernel(
    const u16* __restrict__ xT,
    const u16* __restrict__ wqB, const u16* __restrict__ wkB,
    const u16* __restrict__ wvB,
    const float* __restrict__ bq, const float* __restrict__ bk,
    const float* __restrict__ bv,
    u16* __restrict__ qT, u16* __restrict__ kT, u16* __restrict__ vB)
{
    const int n0 = blockIdx.x * 128;
    const int b  = blockIdx.y;
    const int z  = blockIdx.z;
    const u16* wz = (z == 0) ? wqB : (z == 1) ? wkB : wvB;
    const float* bias = (z == 0) ? bq : (z == 1) ? bk : bv;

    __shared__ u16 Xs[128][72];   // xT tile: rows n0.., 64-K chunk
    __shared__ u16 Ws[128][72];   // w: all 128 rows, 64-K chunk

    const int t  = threadIdx.x;
    const int w  = t >> 6;
    const int l  = t & 63;
    const int lg = l >> 4;
    const int li = l & 15;
    const int cb = w * 32;

    const u16* xTb = xT + (size_t)b * N_TOK * C_DIM;

    // staging coords: tile row = t>>1, col half = (t&1)*32
    const int srow = t >> 1;
    const int sh   = (t & 1) * 32;

    f32x4 acc[8][2];
#pragma unroll
    for (int m = 0; m < 8; ++m)
#pragma unroll
        for (int j = 0; j < 2; ++j)
#pragma unroll
            for (int r = 0; r < 4; ++r) acc[m][j][r] = 0.f;

    // prologue: prefetch chunk 0 into regs
    u16x8 xv[4], wv[4];
#pragma unroll
    for (int g = 0; g < 4; ++g) {
        xv[g] = *(const u16x8a*)&xTb[(size_t)(n0 + srow) * C_DIM + sh + g * 8];
        wv[g] = *(const u16x8a*)&wz[(size_t)srow * C_DIM + sh + g * 8];
    }

    // select fragment sources (role swap for z=2)
    const u16 (*A_lds)[72] = (z < 2) ? Xs : Ws;
    const u16 (*B_lds)[72] = (z < 2) ? Ws : Xs;

#pragma unroll 1
    for (int kk = 0; kk < C_DIM / 64; ++kk) {
        __syncthreads();
#pragma unroll
        for (int g = 0; g < 4; ++g) {
            *(u16x8a*)&Xs[srow][sh + g * 8] = xv[g];
            *(u16x8a*)&Ws[srow][sh + g * 8] = wv[g];
        }
        __syncthreads();

        if (kk + 1 < C_DIM / 64) {
            const int k0 = (kk + 1) * 64;
#pragma unroll
            for (int g = 0; g < 4; ++g) {
                xv[g] = *(const u16x8a*)&xTb[(size_t)(n0 + srow) * C_DIM + k0 + sh + g * 8];
                wv[g] = *(const u16x8a*)&wz[(size_t)srow * C_DIM + k0 + sh + g * 8];
            }
        }

#pragma unroll
        for (int kc = 0; kc < 2; ++kc) {
            bf16x8 af[8], bfv[2];
#pragma unroll
            for (int m = 0; m < 8; ++m)
                af[m] = *(const bf16x8a*)&A_lds[m * 16 + li][kc * 32 + lg * 8];
#pragma unroll
            for (int j = 0; j < 2; ++j)
                bfv[j] = *(const bf16x8a*)&B_lds[cb + j * 16 + li][kc * 32 + lg * 8];
            __builtin_amdgcn_s_setprio(1);
#pragma unroll
            for (int m = 0; m < 8; ++m)
#pragma unroll
                for (int j = 0; j < 2; ++j)
                    acc[m][j] = __builtin_amdgcn_mfma_f32_16x16x32_bf16(
                        af[m], bfv[j], acc[m][j], 0, 0, 0);
            __builtin_amdgcn_s_setprio(0);
        }
    }

    if (z < 2) {
        u16* dst = ((z == 0) ? qT : kT) + (size_t)b * N_TOK * CI_DIM;
#pragma unroll
        for (int j = 0; j < 2; ++j) {
            float bia = bias[cb + j * 16 + li];
#pragma unroll
            for (int m = 0; m < 8; ++m)
#pragma unroll
                for (int r = 0; r < 4; ++r)
                    dst[(size_t)(n0 + m * 16 + lg * 4 + r) * CI_DIM + cb + j * 16 + li] =
                        f2bf(acc[m][j][r] + bia);
        }
    } else {
        u16* dst = vB + (size_t)b * CI_DIM * N_TOK;
#pragma unroll
        for (int m = 0; m < 8; ++m)
#pragma unroll
            for (int r = 0; r < 4; ++r) {
                int o = m * 16 + lg * 4 + r;
                float bia = bias[o];
#pragma unroll
                for (int j = 0; j < 2; ++j)
                    dst[(size_t)o * N_TOK + n0 + cb + j * 16 + li] =
                        f2bf(acc[m][j][r] + bia);
            }
    }
}

// ---------------------------------------------------------------------------
// Kernel B: MFMA flash attention, KV split 4 ways, LDS-staged K/V tiles.
// r11 structure; padding retuned for conflict-free ds_read_b128:
// Ks[32][152] (304B = 19 quads), Vs[128][56] (112B = 7), Ps[4][32][40]
// (80B = 5) -> every 16-row fragment read spans all 8 quad-groups (2-way
// = free). LDS 33.5KB.
// grid = 512 blocks 1-D; x = combo + 16*qb; combo = b + 4*kvh (XCD swizzle).
// ---------------------------------------------------------------------------
__global__ __launch_bounds__(256) void attn_mfma_kernel(
    const u16* __restrict__ qT,   // [B][N][CI]
    const u16* __restrict__ kT,   // [B][N][CI]
    const u16* __restrict__ vB,   // [B][CI][N]
    u16* __restrict__ Opart,      // [4][B][N][CI] bf16, unnormalized
    float* __restrict__ Mout,     // [4][B][N]
    float* __restrict__ Lout)     // [4][B][N]
{
    const int x   = blockIdx.x;
    const int qb  = x >> 4;         // [0,32)
    const int b   = x & 3;          // combo = x & 15 -> same XCD per combo
    const int kvh = (x >> 2) & 3;
    const int j_beg = kvh * (N_TOK / KVSPLIT);

    __shared__ u16 Ks[KVBLK][152];   // K tile, token-major (19-quad stride)
    __shared__ u16 Vs[CI_DIM][56];   // V tile, channel-major (7-quad stride)
    __shared__ u16 Ps[4][32][40];    // per-wave P tile (5-quad stride)

    const int t  = threadIdx.x;
    const int w  = t >> 6;
    const int l  = t & 63;
    const int lg = l >> 4;
    const int li = l & 15;
    const int qw = qb * 128 + w * 32;   // this wave's first query row

    // staging coordinates (coalesced global reads)
    const int krow = t >> 3, kc8 = t & 7;    // K: 32 rows x 8 chunks of 16 u16
    const int vch  = t >> 1, vh  = t & 1;    // V: 128 ch x 2 chunks of 16 u16

    const u16* qTb = qT + (size_t)b * N_TOK * CI_DIM;
    const u16* kTb = kT + (size_t)b * N_TOK * CI_DIM;
    const u16* vBb = vB + (size_t)b * CI_DIM * N_TOK;

    // Q fragments direct from global (once)
    bf16x8 qf[2][4];
#pragma unroll
    for (int qt = 0; qt < 2; ++qt)
#pragma unroll
        for (int kc = 0; kc < 4; ++kc)
            qf[qt][kc] = *(const bf16x8*)&qTb[(size_t)(qw + qt * 16 + li) * CI_DIM + kc * 32 + lg * 8];

    f32x4 Oacc[2][8];
#pragma unroll
    for (int qt = 0; qt < 2; ++qt)
#pragma unroll
        for (int ct = 0; ct < 8; ++ct)
#pragma unroll
            for (int r = 0; r < 4; ++r) Oacc[qt][ct][r] = 0.f;

    float mrun[2] = {-1e30f, -1e30f};
    float lrun[2] = {0.f, 0.f};     // per-lane partials

    // prologue: prefetch tile 0 into regs
    u16x8 kv0, kv1, vv0, vv1;
    {
        const u16* ksrc = &kTb[(size_t)(j_beg + krow) * CI_DIM + kc8 * 16];
        kv0 = *(const u16x8a*)&ksrc[0];
        kv1 = *(const u16x8a*)&ksrc[8];
        const u16* vsrc = &vBb[(size_t)vch * N_TOK + j_beg + vh * 16];
        vv0 = *(const u16x8a*)&vsrc[0];
        vv1 = *(const u16x8a*)&vsrc[8];
    }

#pragma unroll 1
    for (int it = 0; it < NIT; ++it) {
        // (A) all waves done reading previous tile
        __syncthreads();
        *(u16x8a*)&Ks[krow][kc8 * 16]     = kv0;
        *(u16x8a*)&Ks[krow][kc8 * 16 + 8] = kv1;
        *(u16x8a*)&Vs[vch][vh * 16]       = vv0;
        *(u16x8a*)&Vs[vch][vh * 16 + 8]   = vv1;
        // (B) tile ready
        __syncthreads();

        // prefetch next tile into regs; latency hides under compute below
        if (it + 1 < NIT) {
            const int jn = j_beg + (it + 1) * KVBLK;
            const u16* ksrc = &kTb[(size_t)(jn + krow) * CI_DIM + kc8 * 16];
            kv0 = *(const u16x8a*)&ksrc[0];
            kv1 = *(const u16x8a*)&ksrc[8];
            const u16* vsrc = &vBb[(size_t)vch * N_TOK + jn + vh * 16];
            vv0 = *(const u16x8a*)&vsrc[0];
            vv1 = *(const u16x8a*)&vsrc[8];
        }

        // ---- QK^T (swapped): S^T[j][i], fragments from LDS
        bf16x8 ak[2][4];
#pragma unroll
        for (int jt = 0; jt < 2; ++jt)
#pragma unroll
            for (int kc = 0; kc < 4; ++kc)
                ak[jt][kc] = *(const bf16x8a*)&Ks[jt * 16 + li][kc * 32 + lg * 8];

        f32x4 sacc[2][2];
#pragma unroll
        for (int qt = 0; qt < 2; ++qt)
#pragma unroll
            for (int jt = 0; jt < 2; ++jt)
#pragma unroll
                for (int r = 0; r < 4; ++r) sacc[qt][jt][r] = 0.f;
        __builtin_amdgcn_s_setprio(1);
#pragma unroll
        for (int jt = 0; jt < 2; ++jt)
#pragma unroll
            for (int kc = 0; kc < 4; ++kc) {
                sacc[0][jt] = __builtin_amdgcn_mfma_f32_16x16x32_bf16(ak[jt][kc], qf[0][kc], sacc[0][jt], 0, 0, 0);
                sacc[1][jt] = __builtin_amdgcn_mfma_f32_16x16x32_bf16(ak[jt][kc], qf[1][kc], sacc[1][jt], 0, 0, 0);
            }
        __builtin_amdgcn_s_setprio(0);

        // ---- softmax: shuffle-free common path (defer-max)
#pragma unroll
        for (int qt = 0; qt < 2; ++qt) {
            float tl = sacc[qt][0][0];
#pragma unroll
            for (int jt = 0; jt < 2; ++jt)
#pragma unroll
                for (int r = 0; r < 4; ++r) tl = fmaxf(tl, sacc[qt][jt][r]);

            if (__any(tl > mrun[qt] + RESCALE_THR)) {
                float tmax = fmaxf(tl, __shfl_xor(tl, 16));
                tmax = fmaxf(tmax, __shfl_xor(tmax, 32));
                float mold = mrun[qt];
                float mnew = fmaxf(mold, tmax);
                float scale = __expf(mold - mnew);
                lrun[qt] *= scale;
                mrun[qt] = mnew;
#pragma unroll
                for (int r = 0; r < 4; ++r) {
                    float sc_r = __shfl(scale, lg * 4 + r);
#pragma unroll
                    for (int ct = 0; ct < 8; ++ct) Oacc[qt][ct][r] *= sc_r;
                }
            }
            float m = mrun[qt];
            float psum = 0.f;
#pragma unroll
            for (int jt = 0; jt < 2; ++jt) {
                float p0 = __expf(sacc[qt][jt][0] - m);
                float p1 = __expf(sacc[qt][jt][1] - m);
                float p2 = __expf(sacc[qt][jt][2] - m);
                float p3 = __expf(sacc[qt][jt][3] - m);
                psum += (p0 + p1) + (p2 + p3);
                u32 lo = cvt_pk_bf16(p0, p1);
                u32 hi = cvt_pk_bf16(p2, p3);
                u64 pk = (u64)lo | ((u64)hi << 32);
                *(u64a*)&Ps[w][qt * 16 + li][jt * 16 + lg * 4] = pk;
            }
            lrun[qt] += psum;
        }

        // order P stores before PV reads
        asm volatile("" ::: "memory");

        // ---- PV: O^T[i][c] += P[i][j] * V^T[j][c]  (K=32, one slice)
        bf16x8 ap0 = *(const bf16x8a*)&Ps[w][li][lg * 8];
        bf16x8 ap1 = *(const bf16x8a*)&Ps[w][16 + li][lg * 8];
        __builtin_amdgcn_s_setprio(1);
#pragma unroll
        for (int ct = 0; ct < 8; ++ct) {
            bf16x8 bv = *(const bf16x8a*)&Vs[ct * 16 + li][lg * 8];
            Oacc[0][ct] = __builtin_amdgcn_mfma_f32_16x16x32_bf16(ap0, bv, Oacc[0][ct], 0, 0, 0);
            Oacc[1][ct] = __builtin_amdgcn_mfma_f32_16x16x32_bf16(ap1, bv, Oacc[1][ct], 0, 0, 0);
        }
        __builtin_amdgcn_s_setprio(0);
    }

    // ---- epilogue: finish l (cross-lane reduce), write m/l + bf16 O partial
#pragma unroll
    for (int qt = 0; qt < 2; ++qt) {
        lrun[qt] += __shfl_xor(lrun[qt], 16);
        lrun[qt] += __shfl_xor(lrun[qt], 32);
    }
    const size_t mlbase = ((size_t)kvh * B_DIM + b) * N_TOK + qw;
    if (lg == 0) {
#pragma unroll
        for (int qt = 0; qt < 2; ++qt) {
            Mout[mlbase + qt * 16 + li] = mrun[qt];
            Lout[mlbase + qt * 16 + li] = lrun[qt];
        }
    }
    u16* Ob = Opart + mlbase * CI_DIM;
#pragma unroll
    for (int qt = 0; qt < 2; ++qt)
#pragma unroll
        for (int ct = 0; ct < 8; ++ct)
#pragma unroll
            for (int r = 0; r < 4; ++r)
                Ob[(size_t)(qt * 16 + lg * 4 + r) * CI_DIM + ct * 16 + li] =
                    f2bf(Oacc[qt][ct][r]);
}

// ---------------------------------------------------------------------------
// Kernel C: merge the 4 KV-quarter partials -> attnoB bf16 [B][N][CI]
// ---------------------------------------------------------------------------
__global__ __launch_bounds__(256) void attn_merge_kernel(
    const u16* __restrict__ Opart, const float* __restrict__ Mout,
    const float* __restrict__ Lout, u16* __restrict__ attnoB)
{
    const int qb = blockIdx.x;
    const int b  = blockIdx.y;
    const int t  = threadIdx.x;
    const int i  = qb * 64 + (t & 63);
    const int c0 = (t >> 6) * 32;

    size_t ns[KVSPLIT];
    float cs[KVSPLIT];
    float m = -1e30f;
#pragma unroll
    for (int s = 0; s < KVSPLIT; ++s) {
        ns[s] = ((size_t)s * B_DIM + b) * N_TOK + i;
        cs[s] = Mout[ns[s]];
        m = fmaxf(m, cs[s]);
    }
    float den = 0.f;
#pragma unroll
    for (int s = 0; s < KVSPLIT; ++s) {
        cs[s] = __expf(cs[s] - m);
        den += Lout[ns[s]] * cs[s];
    }
    float inv = 1.f / den;
#pragma unroll
    for (int s = 0; s < KVSPLIT; ++s) cs[s] *= inv;

    u16* ab = attnoB + ((size_t)b * N_TOK + i) * CI_DIM;
#pragma unroll
    for (int g = 0; g < 4; ++g) {
        float acc[8];
#pragma unroll
        for (int e = 0; e < 8; ++e) acc[e] = 0.f;
#pragma unroll
        for (int s = 0; s < KVSPLIT; ++s) {
            u16x8 ov = *(const u16x8*)&Opart[ns[s] * CI_DIM + c0 + g * 8];
#pragma unroll
            for (int e = 0; e < 8; ++e) acc[e] += bf2f(ov[e]) * cs[s];
        }
        u16x8 res;
#pragma unroll
        for (int e = 0; e < 8; ++e) res[e] = f2bf(acc[e]);
        *(u16x8*)&ab[c0 + g * 8] = res;
    }
}

// ---------------------------------------------------------------------------
// Kernel D: output projection via MFMA + bias + residual, fp32 out.
// ---------------------------------------------------------------------------
__global__ __launch_bounds__(256) void out_gemm_kernel(
    const u16* __restrict__ attnoB,  // [B][N][CI] bf16
    const u16* __restrict__ woB,     // [C][CI] bf16
    const float* __restrict__ bo,    // [C]
    const float* __restrict__ x,     // [B][C][N]
    float* __restrict__ out)         // [B][C][N]
{
    const int n0 = blockIdx.x * 64;
    const int b  = blockIdx.y;
    const int t  = threadIdx.x;
    const int w  = t >> 6;
    const int l  = t & 63;
    const int lg = l >> 4;
    const int li = l & 15;
    const int co0 = w * 128;

    const u16* ab = attnoB + (size_t)b * N_TOK * CI_DIM;

    f32x4 acc[8][4];
#pragma unroll
    for (int m = 0; m < 8; ++m)
#pragma unroll
        for (int j = 0; j < 4; ++j)
#pragma unroll
            for (int r = 0; r < 4; ++r) acc[m][j][r] = 0.f;

    const u16* Abase = woB + (size_t)(co0 + li) * CI_DIM + lg * 8;
    const u16* Bbase = ab + (size_t)(n0 + li) * CI_DIM + lg * 8;

#pragma unroll
    for (int kk = 0; kk < 4; ++kk) {
        bf16x8 af[8], bfv[4];
#pragma unroll
        for (int m = 0; m < 8; ++m)
            af[m] = *(const bf16x8*)&Abase[(size_t)(m * 16) * CI_DIM + kk * 32];
#pragma unroll
        for (int j = 0; j < 4; ++j)
            bfv[j] = *(const bf16x8*)&Bbase[(size_t)(j * 16) * CI_DIM + kk * 32];
#pragma unroll
        for (int m = 0; m < 8; ++m)
#pragma unroll
            for (int j = 0; j < 4; ++j)
                acc[m][j] = __builtin_amdgcn_mfma_f32_16x16x32_bf16(
                    af[m], bfv[j], acc[m][j], 0, 0, 0);
    }

    const size_t base = (size_t)b * C_DIM * N_TOK;
#pragma unroll
    for (int m = 0; m < 8; ++m)
#pragma unroll
        for (int r = 0; r < 4; ++r) {
            int co = co0 + m * 16 + lg * 4 + r;
            float bia = bo[co];
#pragma unroll
            for (int j = 0; j < 4; ++j) {
                size_t idx = base + (size_t)co * N_TOK + n0 + j * 16 + li;
                out[idx] = acc[m][j][r] + bia + x[idx];
            }
        }
}

extern "C" void kernel_launch(void* const* d_in, const int* in_sizes, int n_in,
                              void* d_out, int out_size, void* d_ws, size_t ws_size,
                              hipStream_t stream) {
    const float* x  = (const float*)d_in[0];
    const float* wq = (const float*)d_in[1];
    const float* bq = (const float*)d_in[2];
    const float* wk = (const float*)d_in[3];
    const float* bk = (const float*)d_in[4];
    const float* wv = (const float*)d_in[5];
    const float* bv = (const float*)d_in[6];
    const float* wo = (const float*)d_in[7];
    const float* bo = (const float*)d_in[8];
    float* out = (float*)d_out;

    // workspace layout (bytes):
    //  [0,16M)         xT bf16 [B][N][C]  -- dead after qkv_gemm; reused as
    //                  Opart bf16 [4][B][N][CI] (exactly 16 MB)
    //  [16M,16.5M)     wqB/wkB/wvB/woB bf16 (128K each)
    //  [16.5M,20.5M)   qT bf16 [B][N][CI]
    //  [20.5M,24.5M)   kT bf16 [B][N][CI]
    //  [24.5M,28.5M)   vB bf16 [B][CI][N]
    //  [28.5M,+512K)   Mout/Lout f32 [4][B][N] (256K each)
    //  [29M,33M)       attnoB bf16 [B][N][CI]
    char* ws = (char*)d_ws;
    const size_t MB = 1024 * 1024;
    u16*   xT    = (u16*)(ws);
    u16*   Opart = (u16*)(ws);                   // aliases xT (16 MB, exact)
    u16*   wqB   = (u16*)(ws + 16 * MB);
    u16*   wkB   = (u16*)(ws + 16 * MB + 128 * 1024);
    u16*   wvB   = (u16*)(ws + 16 * MB + 256 * 1024);
    u16*   woB   = (u16*)(ws + 16 * MB + 384 * 1024);
    u16*   qT    = (u16*)(ws + 16 * MB + 512 * 1024);
    u16*   kT    = (u16*)(ws + 20 * MB + 512 * 1024);
    u16*   vB    = (u16*)(ws + 24 * MB + 512 * 1024);
    float* Mout  = (float*)(ws + 28 * MB + 512 * 1024);
    float* Lout  = (float*)(ws + 28 * MB + 768 * 1024);
    u16*  attnoB = (u16*)(ws + 29 * MB);

    xpose_kernel<<<dim3(64, 8, 4), 256, 0, stream>>>(x, xT);
    wconv_kernel<<<dim3(32, 4), 256, 0, stream>>>(
        wq, wk, wv, wo, wqB, wkB, wvB, woB);
    qkv_gemm_kernel<<<dim3(32, 4, 3), 256, 0, stream>>>(
        xT, wqB, wkB, wvB, bq, bk, bv, qT, kT, vB);
    attn_mfma_kernel<<<dim3(512), 256, 0, stream>>>(
        qT, kT, vB, Opart, Mout, Lout);
    attn_merge_kernel<<<dim3(64, 4), 256, 0, stream>>>(
        Opart, Mout, Lout, attnoB);
    out_gemm_kernel<<<dim3(64, 4), 256, 0, stream>>>(
        attnoB, woB, bo, x, out);
}